// Round 3
// baseline (517.618 us; speedup 1.0000x reference)
//
#include <hip/hip_runtime.h>

#define TOK 64
#define DIMS 256
#define NHEAD 8
#define HDIM 32
#define NWIN 2048

typedef __attribute__((ext_vector_type(8))) short short8;
typedef __attribute__((ext_vector_type(4))) float floatx4;
typedef __attribute__((ext_vector_type(2))) unsigned int uintx2;

__device__ __forceinline__ unsigned short f2bf(float f) {
  unsigned int u = __float_as_uint(f);
  u += 0x7fffu + ((u >> 16) & 1u);   // round-to-nearest-even
  return (unsigned short)(u >> 16);
}

// ---- prep: W->bf16 (scale folded into Wq/bq), rel_bias gather transposed [h][j][i]
__global__ void prep_w(const float* __restrict__ wq, const float* __restrict__ bq,
                       const float* __restrict__ wk, const float* __restrict__ bk,
                       const float* __restrict__ wv, const float* __restrict__ bv,
                       const float* __restrict__ bias_table, const int* __restrict__ rel_index,
                       unsigned short* __restrict__ Wqkv, float* __restrict__ bias,
                       float* __restrict__ rbT) {
  const int o = blockIdx.x;      // 0..767  (output feature row of [768][256])
  const int t = threadIdx.x;     // 0..255
  const float scale = 0.17677669529663687f;  // 1/sqrt(32)
  const float* src; float s;
  if (o < 256)      { src = wq + o * 256;         s = scale; }
  else if (o < 512) { src = wk + (o - 256) * 256; s = 1.0f; }
  else              { src = wv + (o - 512) * 256; s = 1.0f; }
  Wqkv[o * 256 + t] = f2bf(src[t] * s);
  if (o == 0)      bias[t]       = bq[t] * scale;
  else if (o == 1) bias[256 + t] = bk[t];
  else if (o == 2) bias[512 + t] = bv[t];
  if (o < 128) {
    int idx = o * 256 + t;            // = h*4096 + j*64 + i
    int h = idx >> 12, j = (idx >> 6) & 63, i = idx & 63;
    rbT[idx] = bias_table[rel_index[i * 64 + j] * 8 + h];
  }
}

// ---- prep: transpose mask to [w][j][i] via LDS tile (coalesced both ways)
__global__ void prep_maskT(const float* __restrict__ mask, float* __restrict__ maskT) {
  __shared__ float sT[64 * 65];
  const int w = blockIdx.x, t = threadIdx.x;
  #pragma unroll
  for (int it = 0; it < 16; ++it) {
    int idx = it * 256 + t;                       // i*64 + j
    sT[(idx >> 6) * 65 + (idx & 63)] = mask[(w << 12) + idx];
  }
  __syncthreads();
  #pragma unroll
  for (int it = 0; it < 16; ++it) {
    int idx = it * 256 + t;                       // j*64 + i
    maskT[(w << 12) + idx] = sT[(idx & 63) * 65 + (idx >> 6)];
  }
}

__device__ __forceinline__ short8 load_h32(const float* __restrict__ f) {
  floatx4 a = *(const floatx4*)f;
  floatx4 b = *(const floatx4*)(f + 4);
  union { unsigned short s[8]; short8 v; } pk;
  pk.s[0] = f2bf(a.x); pk.s[1] = f2bf(a.y); pk.s[2] = f2bf(a.z); pk.s[3] = f2bf(a.w);
  pk.s[4] = f2bf(b.x); pk.s[5] = f2bf(b.y); pk.s[6] = f2bf(b.z); pk.s[7] = f2bf(b.w);
  return pk.v;
}

// ---- fused QKV + attention. 128 threads = 2 waves; each wave owns 2 heads,
// processed head-sequentially, wave-private LDS regions.
// Per-wave LDS (shorts): Q[64][40] @0, K[64][40] @2560, VT[32][72] @5120,
// P[64][72] aliases Q+K (@0..4607). Total 7424 shorts = 14848 B/wave.
// __syncthreads() at the two aliased-phase boundaries forces the full
// lgkmcnt drain (round-1-proven discipline) — regions are wave-private, so
// the barriers are pure ordering belts, not cross-wave communication.
__global__ __launch_bounds__(128, 2)
void attn_fused(const float* __restrict__ hidden, const unsigned short* __restrict__ Wqkv,
                const float* __restrict__ bias, const float* __restrict__ rbT,
                const float* __restrict__ maskT, float* __restrict__ out) {
  __shared__ unsigned short sm[2 * 7424];
  const int t    = threadIdx.x;
  const int wvi  = t >> 6;
  const int lane = t & 63;
  const int q    = lane >> 4;
  const int l16  = lane & 15;
  const int b    = blockIdx.x >> 1;
  const int pp   = ((blockIdx.x & 1) << 1) | wvi;  // head-pair 0..3

  unsigned short* sQ  = sm + wvi * 7424;
  unsigned short* sK  = sQ + 2560;
  unsigned short* sVT = sQ + 5120;
  unsigned short* sP  = sQ;                        // aliases Q+K
  const int wmod = b & 63;
  const float* hwin = hidden + (size_t)b * (TOK * DIMS);

  #pragma unroll 1
  for (int rep = 0; rep < 2; ++rep) {
    const int h = pp * 2 + rep;

    // ---------- fused QKV GEMM for head h (K-dim = 256)
    // Q/K swapped operands: C'[d][tok]; V normal: C[tok][d]
    floatx4 aqk[4][4];   // [ct][tt]  ct: 0,1=Q d-tiles; 2,3=K d-tiles
    floatx4 av[4][2];    // [tt][nt]
    #pragma unroll
    for (int ct = 0; ct < 4; ++ct)
      #pragma unroll
      for (int tt = 0; tt < 4; ++tt) aqk[ct][tt] = (floatx4){0.f, 0.f, 0.f, 0.f};
    #pragma unroll
    for (int tt = 0; tt < 4; ++tt) {
      av[tt][0] = (floatx4){0.f, 0.f, 0.f, 0.f};
      av[tt][1] = (floatx4){0.f, 0.f, 0.f, 0.f};
    }
    const unsigned short* wq0 = Wqkv + (32 * h + l16) * 256;
    const unsigned short* wk0 = Wqkv + (256 + 32 * h + l16) * 256;
    const unsigned short* wv0 = Wqkv + (512 + 32 * h + l16) * 256;

    #pragma unroll 1
    for (int kk = 0; kk < 8; ++kk) {
      const int ko = kk * 32 + q * 8;
      short8 hbf[4], wqf[4], wvf[2];
      #pragma unroll
      for (int tt = 0; tt < 4; ++tt)
        hbf[tt] = load_h32(hwin + (16 * tt + l16) * 256 + ko);
      wqf[0] = *(const short8*)(wq0 + ko);
      wqf[1] = *(const short8*)(wq0 + 16 * 256 + ko);
      wqf[2] = *(const short8*)(wk0 + ko);
      wqf[3] = *(const short8*)(wk0 + 16 * 256 + ko);
      wvf[0] = *(const short8*)(wv0 + ko);
      wvf[1] = *(const short8*)(wv0 + 16 * 256 + ko);
      #pragma unroll
      for (int ct = 0; ct < 4; ++ct)
        #pragma unroll
        for (int tt = 0; tt < 4; ++tt)
          aqk[ct][tt] = __builtin_amdgcn_mfma_f32_16x16x32_bf16(wqf[ct], hbf[tt], aqk[ct][tt], 0, 0, 0);
      #pragma unroll
      for (int tt = 0; tt < 4; ++tt)
        #pragma unroll
        for (int nt = 0; nt < 2; ++nt)
          av[tt][nt] = __builtin_amdgcn_mfma_f32_16x16x32_bf16(hbf[tt], wvf[nt], av[tt][nt], 0, 0, 0);
    }

    // ---------- epilogues: vectorized b64 LDS stores
    {
      floatx4 bb[4];
      bb[0] = *(const floatx4*)(bias + 32 * h + q * 4);
      bb[1] = *(const floatx4*)(bias + 32 * h + 16 + q * 4);
      bb[2] = *(const floatx4*)(bias + 256 + 32 * h + q * 4);
      bb[3] = *(const floatx4*)(bias + 256 + 32 * h + 16 + q * 4);
      const float bv0 = bias[512 + 32 * h + l16];
      const float bv1 = bias[512 + 32 * h + 16 + l16];
      #pragma unroll
      for (int ct = 0; ct < 4; ++ct) {
        unsigned short* dst = (ct < 2) ? sQ : sK;
        const int d0 = (ct & 1) * 16 + q * 4;
        #pragma unroll
        for (int tt = 0; tt < 4; ++tt) {
          union { unsigned short s[4]; uintx2 u; } pk;
          #pragma unroll
          for (int r = 0; r < 4; ++r) pk.s[r] = f2bf(aqk[ct][tt][r] + bb[ct][r]);
          *(uintx2*)&dst[(16 * tt + l16) * 40 + d0] = pk.u;
        }
      }
      #pragma unroll
      for (int nt = 0; nt < 2; ++nt) {
        const float bvn = nt ? bv1 : bv0;
        #pragma unroll
        for (int tt = 0; tt < 4; ++tt) {
          union { unsigned short s[4]; uintx2 u; } pk;
          #pragma unroll
          for (int r = 0; r < 4; ++r) pk.s[r] = f2bf(av[tt][nt][r] + bvn);
          *(uintx2*)&sVT[(16 * nt + l16) * 72 + 16 * tt + q * 4] = pk.u;
        }
      }
    }
    __syncthreads();   // drain epilogue LDS writes before S-phase reads

    // ---------- S = Q K^T  (scale folded into Q)
    short8 qf[4], kf[4];
    #pragma unroll
    for (int mt = 0; mt < 4; ++mt)
      qf[mt] = *(const short8*)&sQ[(16 * mt + l16) * 40 + q * 8];
    #pragma unroll
    for (int nt = 0; nt < 4; ++nt)
      kf[nt] = *(const short8*)&sK[(16 * nt + l16) * 40 + q * 8];
    floatx4 sacc[4][4];
    #pragma unroll
    for (int mt = 0; mt < 4; ++mt)
      #pragma unroll
      for (int nt = 0; nt < 4; ++nt)
        sacc[mt][nt] = (floatx4){0.f, 0.f, 0.f, 0.f};
    #pragma unroll
    for (int nt = 0; nt < 4; ++nt)
      #pragma unroll
      for (int mt = 0; mt < 4; ++mt)
        sacc[mt][nt] = __builtin_amdgcn_mfma_f32_16x16x32_bf16(qf[mt], kf[nt], sacc[mt][nt], 0, 0, 0);

    // + rel_bias + mask ([.][j][i] layouts -> float4 over the 4 C-regs)
    const float* rb = rbT + h * 4096;
    const float* mw = maskT + wmod * 4096;
    #pragma unroll
    for (int mt = 0; mt < 4; ++mt) {
      const int i0 = 16 * mt + q * 4;
      #pragma unroll
      for (int nt = 0; nt < 4; ++nt) {
        const int j = 16 * nt + l16;
        floatx4 rv = *(const floatx4*)(rb + j * 64 + i0);
        floatx4 mv = *(const floatx4*)(mw + j * 64 + i0);
        sacc[mt][nt] += rv + mv;
      }
    }

    // ---------- softmax over j (rows live in 16-lane groups)
    #pragma unroll
    for (int mt = 0; mt < 4; ++mt) {
      #pragma unroll
      for (int r = 0; r < 4; ++r) {
        float v0 = sacc[mt][0][r], v1 = sacc[mt][1][r];
        float v2 = sacc[mt][2][r], v3 = sacc[mt][3][r];
        float mx = fmaxf(fmaxf(v0, v1), fmaxf(v2, v3));
        mx = fmaxf(mx, __shfl_xor(mx, 1));
        mx = fmaxf(mx, __shfl_xor(mx, 2));
        mx = fmaxf(mx, __shfl_xor(mx, 4));
        mx = fmaxf(mx, __shfl_xor(mx, 8));
        float e0 = __expf(v0 - mx), e1 = __expf(v1 - mx);
        float e2 = __expf(v2 - mx), e3 = __expf(v3 - mx);
        float sm2 = (e0 + e1) + (e2 + e3);
        sm2 += __shfl_xor(sm2, 1);
        sm2 += __shfl_xor(sm2, 2);
        sm2 += __shfl_xor(sm2, 4);
        sm2 += __shfl_xor(sm2, 8);
        const float inv = __builtin_amdgcn_rcpf(sm2);
        sacc[mt][0][r] = e0 * inv; sacc[mt][1][r] = e1 * inv;
        sacc[mt][2][r] = e2 * inv; sacc[mt][3][r] = e3 * inv;
      }
    }

    // ---------- P -> LDS [i][j] (aliases Q+K; qf/kf already consumed)
    #pragma unroll
    for (int mt = 0; mt < 4; ++mt) {
      const int i0 = 16 * mt + q * 4;
      #pragma unroll
      for (int nt = 0; nt < 4; ++nt) {
        const int j = 16 * nt + l16;
        #pragma unroll
        for (int r = 0; r < 4; ++r)
          sP[(i0 + r) * 72 + j] = f2bf(sacc[mt][nt][r]);
      }
    }
    __syncthreads();   // drain P writes before PV reads (and before next rep)

    // ---------- ctx = P V
    floatx4 cacc[4][2];
    #pragma unroll
    for (int mt = 0; mt < 4; ++mt) {
      cacc[mt][0] = (floatx4){0.f, 0.f, 0.f, 0.f};
      cacc[mt][1] = (floatx4){0.f, 0.f, 0.f, 0.f};
    }
    #pragma unroll
    for (int kk = 0; kk < 2; ++kk) {
      const int joff = kk * 32 + q * 8;
      short8 pf[4];
      #pragma unroll
      for (int mt = 0; mt < 4; ++mt)
        pf[mt] = *(const short8*)&sP[(16 * mt + l16) * 72 + joff];
      #pragma unroll
      for (int dt = 0; dt < 2; ++dt) {
        const short8 vf = *(const short8*)&sVT[(16 * dt + l16) * 72 + joff];
        #pragma unroll
        for (int mt = 0; mt < 4; ++mt)
          cacc[mt][dt] = __builtin_amdgcn_mfma_f32_16x16x32_bf16(pf[mt], vf, cacc[mt][dt], 0, 0, 0);
      }
    }

    // ---------- store ctx (fp32)
    float* ob = out + (size_t)b * (TOK * DIMS) + h * 32;
    #pragma unroll
    for (int mt = 0; mt < 4; ++mt) {
      const int i0 = 16 * mt + q * 4;
      #pragma unroll
      for (int dt = 0; dt < 2; ++dt) {
        #pragma unroll
        for (int r = 0; r < 4; ++r)
          ob[(i0 + r) * 256 + dt * 16 + l16] = cacc[mt][dt][r];
      }
    }
  }
}

extern "C" void kernel_launch(void* const* d_in, const int* in_sizes, int n_in,
                              void* d_out, int out_size, void* d_ws, size_t ws_size,
                              hipStream_t stream) {
  const float* hidden = (const float*)d_in[0];
  const float* mask   = (const float*)d_in[1];
  const float* wq = (const float*)d_in[2];
  const float* bq = (const float*)d_in[3];
  const float* wk = (const float*)d_in[4];
  const float* bk = (const float*)d_in[5];
  const float* wv = (const float*)d_in[6];
  const float* bv = (const float*)d_in[7];
  const float* bias_table = (const float*)d_in[8];
  const int*   rel_index  = (const int*)d_in[9];

  char* ws = (char*)d_ws;
  unsigned short* Wqkv = (unsigned short*)ws;               // 393216 B
  float* bias  = (float*)(ws + 393216);                     //   4096 B
  float* rbT   = (float*)(ws + 393216 + 4096);              // 131072 B
  float* maskT = (float*)(ws + 393216 + 4096 + 131072);     // 1048576 B

  prep_w<<<768, 256, 0, stream>>>(wq, bq, wk, bk, wv, bv, bias_table, rel_index,
                                  Wqkv, bias, rbT);
  prep_maskT<<<64, 256, 0, stream>>>(mask, maskT);
  attn_fused<<<NWIN * 2, 128, 0, stream>>>(hidden, Wqkv, bias, rbT, maskT, (float*)d_out);
}